// Round 7
// baseline (706.761 us; speedup 1.0000x reference)
//
#include <hip/hip_runtime.h>
#include <hip/hip_bf16.h>

// Problem constants
#define Lc 256
#define Bc 64
#define Dc 1024
#define Hc 512
#define Rc 8
#define Cc 6
#define WINc 10
#define NWc 21
#define Nc (Bc*Lc)        // 16384
#define DHc (Dc+Hc)       // 1536
#define CH 8192           // RGCN chunk (32 conversations)

typedef __attribute__((ext_vector_type(8))) short short8;
typedef __attribute__((ext_vector_type(4))) float floatx4;

__device__ inline unsigned short f2b(float x) {
    __hip_bfloat16 h = __float2bfloat16(x);
    return *reinterpret_cast<unsigned short*>(&h);
}
__device__ inline float bf2f(unsigned short u) {
    __hip_bfloat16 h;
    *reinterpret_cast<unsigned short*>(&h) = u;
    return __bfloat162float(h);
}

// node id n = b*256+s  ->  feats row s*64+b
__device__ inline long remap_row(int node) { return (long)(((node & 255) << 6) + (node >> 8)); }

typedef __attribute__((address_space(3))) unsigned int lds_u32;
typedef __attribute__((address_space(1))) unsigned int glb_u32;
__device__ inline void glds16(const unsigned short* g, unsigned short* l) {
    __builtin_amdgcn_global_load_lds((const glb_u32*)g, (lds_u32*)l, 16, 0, 0);
}

#define SB0 __builtin_amdgcn_sched_barrier(0)
#define BAR __builtin_amdgcn_s_barrier()

// bijective XCD-aware remap (m204): x-inner so one XCD sweeps all col-tiles of its rows
// (A-panel stays hot in its L2; verified round 4: FETCH 204->75 MB).
__device__ __forceinline__ void xcd_remap(int gridX, int& x, int& y)
{
    int nwg = gridDim.x * gridDim.y;
    int bid = blockIdx.y * gridDim.x + blockIdx.x;
    int q = nwg >> 3, r = nwg & 7;
    int xcd = bid & 7, pos = bid >> 3;
    int logical = xcd * q + min(xcd, r) + pos;
    x = logical % gridX;
    y = logical / gridX;
}

// ---------------- merged prep: weight transposes + em_x + speaker partition (1 launch) ----------
__global__ __launch_bounds__(256) void prep_all(
    const float* __restrict__ Wscalar, const float* __restrict__ W_rel,
    const float* __restrict__ W_root, const float* __restrict__ W_nbr,
    const float* __restrict__ W_self, const float* __restrict__ W_match,
    const float* __restrict__ W_lin, unsigned short* __restrict__ WT,
    const int* __restrict__ spk, int* __restrict__ idx, int* __restrict__ cnts,
    const float* __restrict__ feats, unsigned short* __restrict__ em)
{
    int t = blockIdx.x;
    if (t >= 8448 + 16384) {                     // ---- partition (2 blocks)
        int c = t - (8448 + 16384);
        int tid = threadIdx.x;
        int base = c * CH;
        __shared__ int zs[256];
        int zcount = 0;
        for (int i = 0; i < CH / 256; i++) {
            int n = base + tid * (CH / 256) + i;
            if (spk[(n & 255) * 64 + (n >> 8)] == 0) zcount++;
        }
        zs[tid] = zcount; __syncthreads();
        for (int off = 1; off < 256; off <<= 1) {
            int v = (tid >= off) ? zs[tid - off] : 0;
            __syncthreads();
            zs[tid] += v;
            __syncthreads();
        }
        int Z = zs[255];
        int zpos = zs[tid] - zcount;
        int opos = tid * (CH / 256) - zpos;
        for (int i = 0; i < CH / 256; i++) {
            int nl = tid * (CH / 256) + i;
            int n = base + nl;
            if (spk[(n & 255) * 64 + (n >> 8)] == 0) idx[base + (zpos++)] = nl;
            else                                     idx[base + Z + (opos++)] = nl;
        }
        if (tid == 0) cnts[c] = Z;
        return;
    }
    if (t >= 8448) {                             // ---- em[:,0:1024) = bf16 feats (16384 blocks)
        int n = t - 8448;
        int tid = threadIdx.x;
        const float* f = feats + remap_row(n) * Dc;
        float4 v = ((const float4*)f)[tid];
        unsigned short* e = em + (long)n * DHc + tid * 4;
        e[0] = f2b(v.x); e[1] = f2b(v.y); e[2] = f2b(v.z); e[3] = f2b(v.w);
        return;
    }
    // ---- weight transposes (8448 blocks), fp32 [K][N] -> bf16 [N][K]
    const float* in; unsigned short* out; int N, ldo, n0, k0;
    if (t < 256) {                       // Wscalar [1024][256] -> [256][1024]
        in = Wscalar; out = WT; N = 256; ldo = 1024;
        n0 = (t & 7) * 32; k0 = (t >> 3) * 32;
    } else if (t < 4352) {               // W_rel 8x[1024][512] -> rows r*512..
        int u = t - 256; int r = u >> 9; u &= 511;
        in = W_rel + (long)r * 524288; out = WT + 262144 + (long)r * 524288; N = 512; ldo = 1024;
        n0 = (u & 15) * 32; k0 = (u >> 4) * 32;
    } else if (t < 4864) {               // W_root -> WrelT rows 4096..4608
        int u = t - 4352;
        in = W_root; out = WT + 262144 + 4096 * 1024; N = 512; ldo = 1024;
        n0 = (u & 15) * 32; k0 = (u >> 4) * 32;
    } else if (t < 5120) {               // W_nbr -> WgcT k 0..512
        int u = t - 4864;
        in = W_nbr; out = WT + 4980736; N = 512; ldo = 1024;
        n0 = (u & 15) * 32; k0 = (u >> 4) * 32;
    } else if (t < 5376) {               // W_self -> WgcT k 512..1024
        int u = t - 5120;
        in = W_self; out = WT + 4980736 + 512; N = 512; ldo = 1024;
        n0 = (u & 15) * 32; k0 = (u >> 4) * 32;
    } else if (t < 7680) {               // W_match [1536][1536]
        int u = t - 5376;
        in = W_match; out = WT + 5505024; N = 1536; ldo = 1536;
        n0 = (u % 48) * 32; k0 = (u / 48) * 32;
    } else {                             // W_lin [1536][512] (rows follow W_match: merged B)
        int u = t - 7680;
        in = W_lin; out = WT + 7864320; N = 512; ldo = 1536;
        n0 = (u & 15) * 32; k0 = (u >> 4) * 32;
    }
    __shared__ float tt[32][33];
    int tx = threadIdx.x & 31, ty = threadIdx.x >> 5;
    #pragma unroll
    for (int i = 0; i < 4; i++) tt[ty + i * 8][tx] = in[(long)(k0 + ty + i * 8) * N + n0 + tx];
    __syncthreads();
    #pragma unroll
    for (int i = 0; i < 4; i++) out[(long)(n0 + ty + i * 8) * ldo + k0 + tx] = f2b(tt[tx][ty + i * 8]);
}

// ---------------- 128^2 MFMA GEMM, async staging (small/batched shapes) ----------------
template<bool CBF, bool CT, bool BIAS, bool RELU>
__global__ __launch_bounds__(256) void gemm_as(
    const unsigned short* __restrict__ A, const unsigned short* __restrict__ B,
    void* __restrict__ Cv, const float* __restrict__ bias,
    int K, int lda, int ldb, int ldc, long sA, long sB, long sC)
{
    __shared__ __align__(16) unsigned short As[4096];
    __shared__ __align__(16) unsigned short Bs[4096];
    const int tid = threadIdx.x;
    const int z = blockIdx.z;
    const int m0 = blockIdx.y * 128, n0 = blockIdx.x * 128;
    const int lane = tid & 63, wave = tid >> 6;
    const int q = lane >> 4, mr = lane & 15;
    const int wrow = (wave >> 1) * 64, wcol = (wave & 1) * 64;

    const unsigned short* Ag0 = A + z * sA + (long)(m0 + wave * 32 + mr) * lda + q * 8;
    const unsigned short* Ag1 = Ag0 + (long)16 * lda;
    const unsigned short* Bg0 = B + z * sB + (long)(n0 + wave * 32 + mr) * ldb + q * 8;
    const unsigned short* Bg1 = Bg0 + (long)16 * ldb;
    unsigned short* Al0 = As + wave * 1024;
    unsigned short* Bl0 = Bs + wave * 1024;

    floatx4 acc[4][4];
    #pragma unroll
    for (int mt = 0; mt < 4; mt++)
        #pragma unroll
        for (int nt = 0; nt < 4; nt++) acc[mt][nt] = (floatx4){0.f, 0.f, 0.f, 0.f};

    const int ga = (wave >> 1) * 2048;
    const int gb = (wave & 1) * 2048;

    for (int k0 = 0; k0 < K; k0 += 32) {
        glds16(Ag0 + k0, Al0);
        glds16(Ag1 + k0, Al0 + 512);
        glds16(Bg0 + k0, Bl0);
        glds16(Bg1 + k0, Bl0 + 512);
        __syncthreads();
        short8 af[4], bfr[4];
        #pragma unroll
        for (int t = 0; t < 4; t++) {
            af[t]  = *(const short8*)&As[ga + t * 512 + lane * 8];
            bfr[t] = *(const short8*)&Bs[gb + t * 512 + lane * 8];
        }
        #pragma unroll
        for (int mt = 0; mt < 4; mt++)
            #pragma unroll
            for (int nt = 0; nt < 4; nt++)
                acc[mt][nt] = __builtin_amdgcn_mfma_f32_16x16x32_bf16(af[mt], bfr[nt], acc[mt][nt], 0, 0, 0);
        __syncthreads();
    }

    float* Cf = (float*)Cv;
    unsigned short* Cb = (unsigned short*)Cv;
    #pragma unroll
    for (int mt = 0; mt < 4; mt++) {
        #pragma unroll
        for (int nt = 0; nt < 4; nt++) {
            int col = n0 + wcol + nt * 16 + mr;
            float bv = BIAS ? bias[col] : 0.f;
            #pragma unroll
            for (int rg = 0; rg < 4; rg++) {
                int row = m0 + wrow + mt * 16 + q * 4 + rg;
                float v = acc[mt][nt][rg] + bv;
                if (RELU) v = fmaxf(v, 0.f);
                if (CT) {
                    Cb[(long)(row >> 8) * 131072 + (long)col * 256 + (row & 255)] = f2b(v);
                } else {
                    long ci = z * sC + (long)row * ldc + col;
                    if (CBF) Cb[ci] = f2b(v);
                    else     Cf[ci] = v;
                }
            }
        }
    }
}

// ================= 256^2 8-wave engine core — SINGLE barrier per phase ==================
// (frozen: rounds 3-6 show this engine at ~41% MfmaUtil regardless of schedule variant)
#define MFMA16(ACCBASE, AFR, BFR) \
    { _Pragma("unroll") \
      for (int mt = 0; mt < 4; mt++) \
        _Pragma("unroll") \
        for (int nt = 0; nt < 4; nt++) \
            acc[ACCBASE + mt][nt] = __builtin_amdgcn_mfma_f32_16x16x32_bf16(AFR[mt], BFR[nt], acc[ACCBASE + mt][nt], 0, 0, 0); }

__device__ __forceinline__ void gemm256_loop(
    unsigned short* lp,
    const unsigned short* Ag0, const unsigned short* Ag1,
    const unsigned short* Bg0, const unsigned short* Bg1,
    int NT, int wofs, const int* offA, const int* offB, floatx4 (&acc)[8][4])
{
    unsigned short* Bl = lp + 32768;
    // prologue: t0 all 4 slots; t1 {Bkh0, Bkh1, Akh0}  (t1.Akh1 staged at (0,P0))
    glds16(Ag0,      lp + wofs);                glds16(Ag1,      lp + wofs + 4096);
    glds16(Ag0 + 32, lp + 8192 + wofs);         glds16(Ag1 + 32, lp + 8192 + wofs + 4096);
    glds16(Bg0,      Bl + wofs);                glds16(Bg1,      Bl + wofs + 4096);
    glds16(Bg0 + 32, Bl + 8192 + wofs);         glds16(Bg1 + 32, Bl + 8192 + wofs + 4096);
    glds16(Bg0 + 64, Bl + 16384 + wofs);        glds16(Bg1 + 64, Bl + 16384 + wofs + 4096);
    glds16(Bg0 + 96, Bl + 16384 + 8192 + wofs); glds16(Bg1 + 96, Bl + 16384 + 8192 + wofs + 4096);
    glds16(Ag0 + 64, lp + 16384 + wofs);        glds16(Ag1 + 64, lp + 16384 + wofs + 4096);
    asm volatile("s_waitcnt vmcnt(6)" ::: "memory");   // t0 complete; t1's 6 in flight

    short8 aF[4], bQ[4], b2Q[4];
    for (int t = 0; t < NT; t++) {
        const int buf = t & 1;
        const int ab  = buf * 16384;
        const int abx = (buf ^ 1) * 16384;

        // ===== P0: reads aF(kh0 mt0-3) + bQ(kh0, held 2 phases); stage Akh1(t+1)
        SB0; BAR; SB0;
        #pragma unroll
        for (int i = 0; i < 4; i++) aF[i] = *(const short8*)(lp + ab + offA[i]);
        #pragma unroll
        for (int i = 0; i < 4; i++) bQ[i] = *(const short8*)(Bl + ab + offB[i]);
        if (t + 1 < NT) {
            const int kc = (t + 1) * 64 + 32;
            glds16(Ag0 + kc, lp + abx + 8192 + wofs);
            glds16(Ag1 + kc, lp + abx + 8192 + wofs + 4096);
        }
        asm volatile("s_waitcnt lgkmcnt(0)" ::: "memory"); SB0;
        __builtin_amdgcn_s_setprio(1);
        MFMA16(0, aF, bQ)
        __builtin_amdgcn_s_setprio(0);

        // ===== P1: reads aF(kh0 mt4-7) + b2Q(kh1, held 2 phases); stage Bkh0(t+2)
        SB0; BAR; SB0;
        #pragma unroll
        for (int i = 0; i < 4; i++) aF[i]  = *(const short8*)(lp + ab + offA[4 + i]);
        #pragma unroll
        for (int i = 0; i < 4; i++) b2Q[i] = *(const short8*)(Bl + ab + 8192 + offB[i]);
        if (t + 2 < NT) {
            const int kc = (t + 2) * 64;
            glds16(Bg0 + kc, Bl + ab + wofs);
            glds16(Bg1 + kc, Bl + ab + wofs + 4096);
        }
        asm volatile("s_waitcnt lgkmcnt(0)" ::: "memory"); SB0;
        __builtin_amdgcn_s_setprio(1);
        MFMA16(4, aF, bQ)
        __builtin_amdgcn_s_setprio(0);

        // ===== P2: reads aF(kh1 mt0-3); stage Bkh1(t+2)
        SB0; BAR; SB0;
        #pragma unroll
        for (int i = 0; i < 4; i++) aF[i] = *(const short8*)(lp + ab + 8192 + offA[i]);
        if (t + 2 < NT) {
            const int kc = (t + 2) * 64 + 32;
            glds16(Bg0 + kc, Bl + ab + 8192 + wofs);
            glds16(Bg1 + kc, Bl + ab + 8192 + wofs + 4096);
        }
        asm volatile("s_waitcnt lgkmcnt(0)" ::: "memory"); SB0;
        __builtin_amdgcn_s_setprio(1);
        MFMA16(0, aF, b2Q)
        __builtin_amdgcn_s_setprio(0);

        // ===== P3: reads aF(kh1 mt4-7); stage Akh0(t+2); counted vmcnt(6)
        SB0; BAR; SB0;
        #pragma unroll
        for (int i = 0; i < 4; i++) aF[i] = *(const short8*)(lp + ab + 8192 + offA[4 + i]);
        if (t + 2 < NT) {
            const int kc = (t + 2) * 64;
            glds16(Ag0 + kc, lp + ab + wofs);
            glds16(Ag1 + kc, lp + ab + wofs + 4096);
        }
        if (t < NT - 2)       { asm volatile("s_waitcnt vmcnt(6)" ::: "memory"); }
        else if (t == NT - 2) { asm volatile("s_waitcnt vmcnt(0)" ::: "memory"); }
        asm volatile("s_waitcnt lgkmcnt(0)" ::: "memory"); SB0;
        __builtin_amdgcn_s_setprio(1);
        MFMA16(4, aF, b2Q)
        __builtin_amdgcn_s_setprio(0);
    }
}

// helper: per-kernel fragment offsets (XOR-swizzled, matches pre-swizzled global source)
__device__ __forceinline__ void frag_offsets(int wm, int wn, int q, int mr, int* offA, int* offB)
{
    #pragma unroll
    for (int mt = 0; mt < 8; mt++) {
        int row = wm * 128 + mt * 16 + mr;
        offA[mt] = row * 32 + ((q ^ ((row >> 1) & 3)) * 8);
    }
    #pragma unroll
    for (int nt = 0; nt < 4; nt++) {
        int row = wn * 64 + nt * 16 + mr;
        offB[nt] = row * 32 + ((q ^ ((row >> 1) & 3)) * 8);
    }
}

// ---------------- generic 256^2 GEMM (used for h2) ----------------
template<bool CBF, bool CT, bool BIAS, bool RELU>
__global__ __launch_bounds__(512, 2) void gemm256(
    const unsigned short* __restrict__ A, const unsigned short* __restrict__ B,
    void* __restrict__ Cv, const float* __restrict__ bias,
    int K, int lda, int ldb, int ldc)
{
    __shared__ __align__(16) unsigned short LDS[65536];
    unsigned short* lp = &LDS[0];
    const int tid  = threadIdx.x;
    const int lane = tid & 63, wave = tid >> 6;
    const int wm = wave >> 2, wn = wave & 3;
    int bx, by;
    xcd_remap(gridDim.x, bx, by);
    const int m0 = by * 256, n0 = bx * 256;
    const int NT = K >> 6;
    const int q = lane >> 4, mr = lane & 15;

    const int r0 = wave * 16 + (lane >> 2);
    const int r1 = r0 + 128;
    const int c0 = ((lane & 3) ^ ((r0 >> 1) & 3)) * 8;
    const int c1 = ((lane & 3) ^ ((r1 >> 1) & 3)) * 8;
    const unsigned short* Ag0 = A + (long)(m0 + r0) * lda + c0;
    const unsigned short* Ag1 = A + (long)(m0 + r1) * lda + c1;
    const unsigned short* Bg0 = B + (long)(n0 + r0) * ldb + c0;
    const unsigned short* Bg1 = B + (long)(n0 + r1) * ldb + c1;
    const int wofs = wave * 512;

    int offA[8], offB[4];
    frag_offsets(wm, wn, q, mr, offA, offB);

    floatx4 acc[8][4];
    #pragma unroll
    for (int mt = 0; mt < 8; mt++)
        #pragma unroll
        for (int nt = 0; nt < 4; nt++) acc[mt][nt] = (floatx4){0.f, 0.f, 0.f, 0.f};

    gemm256_loop(lp, Ag0, Ag1, Bg0, Bg1, NT, wofs, offA, offB, acc);

    float* Cf = (float*)Cv;
    unsigned short* Cb = (unsigned short*)Cv;
    #pragma unroll
    for (int mt = 0; mt < 8; mt++) {
        #pragma unroll
        for (int nt = 0; nt < 4; nt++) {
            int col = n0 + wn * 64 + nt * 16 + mr;
            float bv = BIAS ? bias[col] : 0.f;
            #pragma unroll
            for (int rg = 0; rg < 4; rg++) {
                int row = m0 + wm * 128 + mt * 16 + q * 4 + rg;
                float v = acc[mt][nt][rg] + bv;
                if (RELU) v = fmaxf(v, 0.f);
                if (CT) {
                    Cb[(long)(row >> 8) * 131072 + (long)col * 256 + (row & 255)] = f2b(v);
                } else {
                    long ci = (long)row * ldc + col;
                    if (CBF) Cb[ci] = f2b(v);
                    else     Cf[ci] = v;
                }
            }
        }
    }
}

// ---------------- RGCN 256^2: both speaker segments + root in ONE dispatch per chunk -----------
__global__ __launch_bounds__(512, 2) void rgcn256(
    const unsigned short* __restrict__ A, const unsigned short* __restrict__ B,
    unsigned short* __restrict__ C, const int* __restrict__ idx,
    const int* __restrict__ cntp)
{
    const int cnt0 = *cntp;
    const int t0 = (cnt0 + 255) >> 8;
    const int M1 = CH - cnt0;
    const int t1 = (M1 + 255) >> 8;
    int x, ty;
    xcd_remap(gridDim.x, x, ty);
    int sblk, m0, M, off;
    if (ty < t0)           { sblk = 0; m0 = ty << 8;        M = cnt0; off = 0; }
    else if (ty < t0 + t1) { sblk = 1; m0 = (ty - t0) << 8; M = M1;   off = cnt0; }
    else return;

    const int brow = ((x < 8) ? sblk * 2048 : 2048) + x * 256;   // B row base in WrelT (root at 4096+)

    __shared__ __align__(16) unsigned short LDS[65536];
    unsigned short* lp = &LDS[0];
    const int tid  = threadIdx.x;
    const int lane = tid & 63, wave = tid >> 6;
    const int wm = wave >> 2, wn = wave & 3;
    const int q = lane >> 4, mr = lane & 15;

    const int r0 = wave * 16 + (lane >> 2);
    const int r1 = r0 + 128;
    const int c0 = ((lane & 3) ^ ((r0 >> 1) & 3)) * 8;
    const int c1 = ((lane & 3) ^ ((r1 >> 1) & 3)) * 8;
    const int gr0 = idx[off + min(m0 + r0, M - 1)];
    const int gr1 = idx[off + min(m0 + r1, M - 1)];
    const unsigned short* Ag0 = A + (long)gr0 * DHc + c0;
    const unsigned short* Ag1 = A + (long)gr1 * DHc + c1;
    const unsigned short* Bg0 = B + (long)(brow + r0) * 1024 + c0;
    const unsigned short* Bg1 = B + (long)(brow + r1) * 1024 + c1;
    const int wofs = wave * 512;

    int offA[8], offB[4];
    frag_offsets(wm, wn, q, mr, offA, offB);

    floatx4 acc[8][4];
    #pragma unroll
    for (int mt = 0; mt < 8; mt++)
        #pragma unroll
        for (int nt = 0; nt < 4; nt++) acc[mt][nt] = (floatx4){0.f, 0.f, 0.f, 0.f};

    gemm256_loop(lp, Ag0, Ag1, Bg0, Bg1, 16 /*K=1024*/, wofs, offA, offB, acc);

    #pragma unroll
    for (int mt = 0; mt < 8; mt++) {
        int rowb = m0 + wm * 128 + mt * 16 + q * 4;
        int cr[4];
        #pragma unroll
        for (int rg = 0; rg < 4; rg++) cr[rg] = idx[off + min(rowb + rg, M - 1)];
        #pragma unroll
        for (int nt = 0; nt < 4; nt++) {
            int col = x * 256 + wn * 64 + nt * 16 + mr;
            #pragma unroll
            for (int rg = 0; rg < 4; rg++)
                C[(long)cr[rg] * 2560 + col] = f2b(acc[mt][nt][rg]);
        }
    }
}

// ---------------- merged xt + emW: B = [W_matchT | W_linT] (2048 x 1536 contiguous) -------------
__global__ __launch_bounds__(512, 2) void gemm256_mw(
    const unsigned short* __restrict__ A, const unsigned short* __restrict__ B,
    unsigned short* __restrict__ xt, unsigned short* __restrict__ emWT,
    const float* __restrict__ b_match, const float* __restrict__ b_lin)
{
    __shared__ __align__(16) unsigned short LDS[65536];
    unsigned short* lp = &LDS[0];
    const int tid  = threadIdx.x;
    const int lane = tid & 63, wave = tid >> 6;
    const int wm = wave >> 2, wn = wave & 3;
    int bx, by;
    xcd_remap(gridDim.x, bx, by);
    const int m0 = by * 256, n0 = bx * 256;
    const int q = lane >> 4, mr = lane & 15;

    const int r0 = wave * 16 + (lane >> 2);
    const int r1 = r0 + 128;
    const int c0 = ((lane & 3) ^ ((r0 >> 1) & 3)) * 8;
    const int c1 = ((lane & 3) ^ ((r1 >> 1) & 3)) * 8;
    const unsigned short* Ag0 = A + (long)(m0 + r0) * DHc + c0;
    const unsigned short* Ag1 = A + (long)(m0 + r1) * DHc + c1;
    const unsigned short* Bg0 = B + (long)(n0 + r0) * 1536 + c0;
    const unsigned short* Bg1 = B + (long)(n0 + r1) * 1536 + c1;
    const int wofs = wave * 512;

    int offA[8], offB[4];
    frag_offsets(wm, wn, q, mr, offA, offB);

    floatx4 acc[8][4];
    #pragma unroll
    for (int mt = 0; mt < 8; mt++)
        #pragma unroll
        for (int nt = 0; nt < 4; nt++) acc[mt][nt] = (floatx4){0.f, 0.f, 0.f, 0.f};

    gemm256_loop(lp, Ag0, Ag1, Bg0, Bg1, 24 /*K=1536*/, wofs, offA, offB, acc);

    if (n0 < 1536) {
        #pragma unroll
        for (int mt = 0; mt < 8; mt++) {
            #pragma unroll
            for (int nt = 0; nt < 4; nt++) {
                int col = n0 + wn * 64 + nt * 16 + mr;
                float bv = b_match[col];
                #pragma unroll
                for (int rg = 0; rg < 4; rg++) {
                    int row = m0 + wm * 128 + mt * 16 + q * 4 + rg;
                    xt[(long)row * DHc + col] = f2b(acc[mt][nt][rg] + bv);
                }
            }
        }
    } else {
        #pragma unroll
        for (int mt = 0; mt < 8; mt++) {
            #pragma unroll
            for (int nt = 0; nt < 4; nt++) {
                int col = (n0 - 1536) + wn * 64 + nt * 16 + mr;
                float bv = b_lin[col];
                #pragma unroll
                for (int rg = 0; rg < 4; rg++) {
                    int row = m0 + wm * 128 + mt * 16 + q * 4 + rg;
                    emWT[(long)(row >> 8) * 131072 + (long)col * 256 + (row & 255)] =
                        f2b(acc[mt][nt][rg] + bv);
                }
            }
        }
    }
}

// ---------------- edge_norm: windowed softmax over k (scale node-ordered) ----------------
__global__ __launch_bounds__(256) void edge_norm_kernel(const float* __restrict__ scale,
                                                        float* __restrict__ enorm)
{
    int g = blockIdx.x * 256 + threadIdx.x;   // b*L + j
    int b = g >> 8, j = g & 255;
    int klo = max(0, j - WINc), khi = min(Lc - 1, j + WINc);
    float vals[NWc];
    float m = -1e30f;
    for (int k = klo; k <= khi; k++) {
        float v = scale[(long)((b << 8) + k) * Lc + j];
        vals[k - klo] = v;
        m = fmaxf(m, v);
    }
    float s = 0.f;
    for (int k = klo; k <= khi; k++) {
        float e = expf(vals[k - klo] - m);
        vals[k - klo] = e;
        s += e;
    }
    float inv = 1.f / s;
    for (int k = klo; k <= khi; k++)
        enorm[(long)g * NWc + (k - j + WINc)] = vals[k - klo] * inv;
}

// ---------------- RGCN aggregation, conv-strip LDS-staged (round-7) ----------------
// block = (strip 0..15 of 32 H-cols, conv 0..31). Stage the conv's hall4 rows ONCE:
// 4 c-blocks + root, 32-col strip = 1280 segs x 64B = 80KB, via global_load_lds
// (linear dest = seg order; per-lane source). enorm rows (21KB) + spk (1KB) in LDS too.
// Compute: thread = (u32-pair p 0..15, k-group of 8). FP order identical to old
// rgcn_gather4 (root+bias first, then j ascending) -> bitwise-same h1.
__global__ __launch_bounds__(512) void rgcn_gather256(
    const unsigned short* __restrict__ hall4, const float* __restrict__ enorm,
    const int* __restrict__ spk, const float* __restrict__ b_rgcn,
    float* __restrict__ h1, int chunk_base)
{
    __shared__ __align__(16) unsigned short hs[40960];   // [seg 1280][32 elems]: c0..c3 rows, root rows
    __shared__ float ws[5376];                           // enorm [j 256][21]
    __shared__ int spkS[256];
    const int strip = blockIdx.x;
    const int conv  = blockIdx.y;
    const int b     = (chunk_base >> 8) + conv;
    const int tid = threadIdx.x, lane = tid & 63, wave = tid >> 6;

    #pragma unroll
    for (int cId = 0; cId < 10; cId++) {
        int segBase = cId * 128 + wave * 16;
        int seg = segBase + (lane >> 2);
        int c = seg >> 8, r = seg & 255;
        long src = ((long)conv * 256 + r) * 2560 + (c < 4 ? c * 512 : 2048)
                 + strip * 32 + (lane & 3) * 8;
        glds16(hall4 + src, hs + segBase * 32);
    }
    const float* en = enorm + (((long)b << 8)) * NWc;
    for (int i = tid; i < 5376; i += 512) ws[i] = en[i];
    if (tid < 256) spkS[tid] = spk[tid * Bc + b];
    __syncthreads();

    const int p = tid & 15;
    const int kbase = (tid >> 4) * 8;
    const int colg = strip * 32 + p * 2;
    const float bb0 = b_rgcn[colg], bb1 = b_rgcn[colg + 1];
    for (int kk = 0; kk < 8; kk++) {
        int k = kbase + kk;
        int jlo = max(0, k - WINc), jhi = min(Lc - 1, k + WINc);
        unsigned int ru = *(const unsigned int*)(hs + (1024 + k) * 32 + p * 2);
        float a0 = bf2f((unsigned short)(ru & 0xffff)) + bb0;
        float a1 = bf2f((unsigned short)(ru >> 16)) + bb1;
        int cb = spkS[k] * 2;
        for (int j = jlo; j <= jhi; j++) {
            int c = cb + ((j < k) ? 0 : 1);
            float w = ws[j * NWc + (k - j + WINc)];
            unsigned int u = *(const unsigned int*)(hs + (c * 256 + j) * 32 + p * 2);
            a0 += w * bf2f((unsigned short)(u & 0xffff));
            a1 += w * bf2f((unsigned short)(u >> 16));
        }
        long n = (long)chunk_base + conv * 256 + k;
        *(float2*)&h1[n * Hc + colg] = make_float2(a0, a1);
    }
}

// ---------------- anh1 builder, conv-strip LDS-staged (round-7) ----------------
// block = (strip 0..3 of 128 f32 cols, conv 0..63). Stage h1[conv rows][strip] once
// (128KB linear, glds16-compatible). Thread = (col, k-group of 64): lanes read
// consecutive cols of one row -> conflict-free. FP order identical to old build_anh1.
__global__ __launch_bounds__(512) void build_anh256(const float* __restrict__ h1,
                                                    unsigned short* __restrict__ anh1)
{
    __shared__ __align__(16) float hsf[32768];   // [row 256][col 128]
    const int strip = blockIdx.x;
    const int conv  = blockIdx.y;
    const int tid = threadIdx.x, lane = tid & 63, wave = tid >> 6;

    #pragma unroll
    for (int cId = 0; cId < 16; cId++) {
        int segBase = cId * 128 + wave * 16;
        int seg = segBase + (lane >> 2);
        int r = seg >> 3, sc = seg & 7;
        const float* src = h1 + ((long)conv * 256 + r) * Hc + strip * 128 + sc * 16 + (lane & 3) * 4;
        glds16((const unsigned short*)src, (unsigned short*)(hsf + segBase * 16));
    }
    __syncthreads();

    const int col = tid & 127;
    const int kbase = (tid >> 7) * 64;
    const int colg = strip * 128 + col;
    for (int kk = 0; kk < 64; kk++) {
        int k = kbase + kk;
        int jlo = max(0, k - WINc), jhi = min(Lc - 1, k + WINc);
        float a = 0.f;
        for (int j = jlo; j <= jhi; j++) a += hsf[j * 128 + col];
        float self = hsf[k * 128 + col];
        unsigned short* dst = anh1 + ((long)conv * 256 + k) * 1024;
        dst[colg] = f2b(a);
        dst[512 + colg] = f2b(self);
    }
}

// ---------------- tanh + row softmax -> bf16 attention weights ----------------
__global__ __launch_bounds__(256) void tanh_softmax_rows(const float* __restrict__ S,
                                                         unsigned short* __restrict__ a)
{
    int row = blockIdx.x;
    int tid = threadIdx.x;
    __shared__ float red[256];
    float v = tanhf(S[(long)row * Lc + tid]);
    red[tid] = v; __syncthreads();
    for (int s = 128; s > 0; s >>= 1) { if (tid < s) red[tid] = fmaxf(red[tid], red[tid + s]); __syncthreads(); }
    float m = red[0]; __syncthreads();
    float e = expf(v - m);
    red[tid] = e; __syncthreads();
    for (int s = 128; s > 0; s >>= 1) { if (tid < s) red[tid] += red[tid + s]; __syncthreads(); }
    float sum = red[0];
    a[(long)row * Lc + tid] = f2b(e / sum);
}

// ---------------- final classifier + log_softmax (fp32 out) ----------------
__global__ __launch_bounds__(256) void out_kernel(const unsigned short* __restrict__ hidden,
        const float* __restrict__ Wfc, const float* __restrict__ bfc, float* __restrict__ out)
{
    int tid = threadIdx.x;
    int lane = tid & 63;
    int row = blockIdx.x * 4 + (tid >> 6);
    float acc[Cc] = {};
    const unsigned short* h = hidden + (long)row * Hc;
    for (int k = lane; k < Hc; k += 64) {
        float hv = bf2f(h[k]);
        #pragma unroll
        for (int c = 0; c < Cc; c++) acc[c] += hv * Wfc[k * Cc + c];
    }
    #pragma unroll
    for (int c = 0; c < Cc; c++)
        for (int off = 32; off > 0; off >>= 1) acc[c] += __shfl_down(acc[c], off, 64);
    if (lane == 0) {
        float m = -1e30f;
        #pragma unroll
        for (int c = 0; c < Cc; c++) { acc[c] += bfc[c]; m = fmaxf(m, acc[c]); }
        float s = 0.f;
        #pragma unroll
        for (int c = 0; c < Cc; c++) s += expf(acc[c] - m);
        float lse = logf(s);
        #pragma unroll
        for (int c = 0; c < Cc; c++) out[(long)row * Cc + c] = acc[c] - m - lse;
    }
}

extern "C" void kernel_launch(void* const* d_in, const int* in_sizes, int n_in,
                              void* d_out, int out_size, void* d_ws, size_t ws_size,
                              hipStream_t stream)
{
    const float* feats   = (const float*)d_in[0];
    const float* Wscalar = (const float*)d_in[1];
    const float* W_rel   = (const float*)d_in[2];
    const float* W_root  = (const float*)d_in[3];
    const float* b_rgcn  = (const float*)d_in[4];
    const float* W_nbr   = (const float*)d_in[5];
    const float* W_self  = (const float*)d_in[6];
    const float* b_gc    = (const float*)d_in[7];
    const float* W_match = (const float*)d_in[8];
    const float* b_match = (const float*)d_in[9];
    const float* W_lin   = (const float*)d_in[10];
    const float* b_lin   = (const float*)d_in[11];
    const float* W_fc    = (const float*)d_in[12];
    const float* b_fc    = (const float*)d_in[13];
    const int*   spk     = (const int*)d_in[14];

    char* wsb = (char*)d_ws;
    unsigned short* em    = (unsigned short*)wsb;               // [0,48M) persistent
    char* RB = wsb + 50331648;                                  // time-multiplexed region (48M)
    float*          scale = (float*)RB;                         // 16M  (steps 1-2)
    unsigned short* hall4 = (unsigned short*)RB;                // 41.9M (RGCN loop)
    unsigned short* anh1  = (unsigned short*)RB;                // 32M  (anh1 -> h2)
    unsigned short* xt    = (unsigned short*)RB;                // 48M  (xt -> S)
    unsigned short* hidden= (unsigned short*)(RB + 16777216);   // 16M  (after S; xt dead)
    char* HB = wsb + 100663296;                                 // second region (32M)
    float*          h1    = (float*)HB;                         // 32M (RGCN -> build_anh256; then dead)
    float*          S     = (float*)HB;                         // 16M (step 6 -> 7; h1 dead)
    unsigned short* emWT  = (unsigned short*)(wsb + 117440512); // 16M HB[16,32M) (step 5 -> 9)
    int* idx              = (int*)(HB + 16777216);              // 64K (read before gather(c1) clobbers)
    int* cnts             = (int*)(HB + 16777216 + 65536);      // 8B  (same)
    unsigned short* WT    = (unsigned short*)(wsb + 134217728); // 17.3M persistent (dead after step 5)
    unsigned short* WscalarT = WT;
    unsigned short* WrelT    = WT + 262144;      // 4608x1024: rels 0..7 then root at 4096..4608
    unsigned short* WgcT     = WT + 4980736;     // 512x1024 (nbr k0..512 | self k512..1024)
    unsigned short* WmatchT  = WT + 5505024;     // 1536x1536, then W_lin 512x1536 contiguous
    unsigned short* ac    = (unsigned short*)(wsb + 134217728); // 8M over dead WT head (step 7 -> 9)
    float*          enorm = (float*)(wsb + 151519232);          // 1.31M

    // ---- 0. merged prep: transposes + em_x + partition (1 launch)
    prep_all<<<dim3(8448 + 16384 + 2), 256, 0, stream>>>(
        Wscalar, W_rel, W_root, W_nbr, W_self, W_match, W_lin, WT,
        spk, idx, cnts, feats, em);

    // ---- 1. scale = x @ Wscalar  [16384 x 256]
    gemm_as<false, false, false, false><<<dim3(2, 128, 1), 256, 0, stream>>>(
        em, WscalarT, scale, nullptr, 1024, DHc, 1024, 256, 0, 0, 0);

    // ---- 2. windowed softmax
    edge_norm_kernel<<<dim3(64), 256, 0, stream>>>(scale, enorm);

    // ---- 3. RGCN per chunk: ONE 256^2 dispatch (both speakers + root), then conv-strip gather
    for (int c = 0; c < 2; c++) {
        const unsigned short* emc = em + (long)c * CH * DHc;
        rgcn256<<<dim3(10, 33, 1), 512, 0, stream>>>(
            emc, WrelT, hall4, idx + c * CH, cnts + c);
        rgcn_gather256<<<dim3(16, 32, 1), 512, 0, stream>>>(
            hall4, enorm, spk, b_rgcn, h1, c * CH);
    }

    // ---- 4. anh1 = concat(window-sum(h1), h1); h2 -> em[:, 1024:1536)   [256^2 engine]
    build_anh256<<<dim3(4, 64, 1), 512, 0, stream>>>(h1, anh1);
    gemm256<true, false, true, false><<<dim3(2, 64, 1), 512, 0, stream>>>(
        anh1, WgcT, em + 1024, b_gc, 1024, 1024, 1024, DHc);

    // ---- 5. merged: xt = em @ W_match + b_match  AND  emWT = (em @ W_lin + b_lin)^T per conv
    gemm256_mw<<<dim3(8, 64, 1), 512, 0, stream>>>(
        em, WmatchT, xt, emWT, b_match, b_lin);

    // ---- 6. S_b = xt_b @ em_b^T  (z = 64 convs)
    gemm_as<false, false, false, false><<<dim3(2, 2, 64), 256, 0, stream>>>(
        xt, em, S, nullptr, DHc, DHc, DHc, 256, 393216, 393216, 65536);

    // ---- 7. a = softmax(tanh(S))
    tanh_softmax_rows<<<dim3(Nc), 256, 0, stream>>>(S, ac);

    // ---- 9. hidden = relu(a @ emW)  (z = 64 convs, bf16 out)
    gemm_as<true, false, false, true><<<dim3(4, 2, 64), 256, 0, stream>>>(
        ac, emWT, hidden, nullptr, 256, 256, 256, 512, 65536, 131072, 131072);

    // ---- 10. logits + log_softmax
    out_kernel<<<dim3(Nc / 4), 256, 0, stream>>>(hidden, W_fc, b_fc, (float*)d_out);
}